// Round 5
// baseline (23.149 us; speedup 1.0000x reference)
//
#include <hip/hip_runtime.h>
#include <cstddef>
#include <cstdint>

// RoIPool: features (B=2, C=256, H=50, W=50) f32, rois (R,4) f32, roi_indices (R,) int
// out (R, C, 7, 7) f32.
// Reference quirk preserved: h-bins from x coords (ri[:,0], ri[:,2]), w-bins from y.
//
// Structure: transpose to (CSPLIT=2, B, H, W, 128) channel-last; pool kernel:
// one 448-thread block per (slice, roi), lane = channel-PAIR (float2 loads),
// wave = ph. Out-of-window loads are clamped to duplicate in-window elements
// (max-exact) so the inner loop is pure load+fmax with scalar-uniform addressing.

namespace {
constexpr int OUTP = 7;
constexpr int BB = 2;
constexpr int CC = 256;
constexpr int HH = 50;
constexpr int WW = 50;
constexpr int HWSZ = HH * WW;
constexpr int CSPLIT = 2;
constexpr int CPS = CC / CSPLIT;  // 128 channels per slice
constexpr float NEGV = -3e38f;
typedef float vf2 __attribute__((ext_vector_type(2)));  // clang-native 2-float
}  // namespace

// (B, C, H*W) -> (CSPLIT, B, H*W, CPS) tiled transpose via LDS.
__global__ __launch_bounds__(256) void transpose_k(const float* __restrict__ in,
                                                   float* __restrict__ out) {
    __shared__ float tile[32][33];
    const int b = blockIdx.z;
    const int hw0 = blockIdx.x * 32;
    const int c0 = blockIdx.y * 32;
    const int tx = threadIdx.x;
#pragma unroll
    for (int i = threadIdx.y; i < 32; i += 8) {
        const int hw = hw0 + tx;
        float v = 0.0f;
        if (hw < HWSZ) v = in[(size_t)(b * CC + c0 + i) * HWSZ + hw];
        tile[i][tx] = v;
    }
    __syncthreads();
    const int ch = c0 + tx;           // channel this thread writes
    const int s = ch >> 7;            // slice (0..1)
    const int cin = ch & (CPS - 1);   // channel within slice (contiguous in tx)
#pragma unroll
    for (int i = threadIdx.y; i < 32; i += 8) {
        const int hw = hw0 + i;
        if (hw < HWSZ)
            out[((size_t)((s * BB + b) * HWSZ) + hw) * CPS + cin] = tile[tx][i];
    }
}

// Pool: grid (CSPLIT, R), block 448 = 7 waves; wave = ph, lane = channel pair.
__global__ __launch_bounds__(448) void roipool4(const float* __restrict__ feat,
                                                const float* __restrict__ rois,
                                                const int* __restrict__ ridx,
                                                float* __restrict__ out) {
    const int s = blockIdx.x;
    const int r = blockIdx.y;
    const int tid = threadIdx.x;
    const int c2 = tid & 63;                                  // channel-pair index
    const int ph = __builtin_amdgcn_readfirstlane(tid >> 6);  // wave-uniform

    const float4 rv = reinterpret_cast<const float4*>(rois)[r];
    int x1 = (int)(rv.x * 0.0625f);
    int y1 = (int)(rv.y * 0.0625f);
    int x2 = (int)(rv.z * 0.0625f);
    int y2 = (int)(rv.w * 0.0625f);
    int b = ridx[r];
    x1 = __builtin_amdgcn_readfirstlane(x1);
    y1 = __builtin_amdgcn_readfirstlane(y1);
    x2 = __builtin_amdgcn_readfirstlane(x2);
    y2 = __builtin_amdgcn_readfirstlane(y2);
    b = __builtin_amdgcn_readfirstlane(b);

    const int Lh = x2 - x1;
    const int Lw = y2 - y1;

    int hs = x1 + (ph * Lh) / OUTP;
    int he = x1 + ((ph + 1) * Lh + OUTP - 1) / OUTP;
    hs = hs < 0 ? 0 : hs;
    he = he > HH ? HH : he;
    const int nh = he - hs;

    int ws_[OUTP], nw_[OUTP];
    int mx = nh;
#pragma unroll
    for (int p = 0; p < OUTP; ++p) {
        int a = y1 + (p * Lw) / OUTP;
        int e = y1 + ((p + 1) * Lw + OUTP - 1) / OUTP;
        a = a < 0 ? 0 : a;
        e = e > WW ? WW : e;
        ws_[p] = a;
        nw_[p] = e - a;  // >= 1 for this geometry
        mx = mx > (e - a) ? mx : (e - a);
    }

    vf2 acc[OUTP];
#pragma unroll
    for (int p = 0; p < OUTP; ++p) acc[p] = (vf2){NEGV, NEGV};

    const float* base =
        feat + ((size_t)((s * BB + b) * HWSZ) + (size_t)hs * WW) * CPS + 2 * c2;

    if (mx <= 4) {
        // Fast path (always taken: L = x2-x1 in [4,19] -> per-bin span <= 4).
#pragma unroll
        for (int hh = 0; hh < 4; ++hh) {
            if (hh < nh) {  // scalar branch: skipped rows fetch nothing
                const float* rp = base + (size_t)hh * (WW * CPS);
#pragma unroll
                for (int p = 0; p < OUTP; ++p) {
#pragma unroll
                    for (int ww = 0; ww < 4; ++ww) {
                        // Duplicate-clamp: out-of-window reloads an in-window
                        // element -> max unchanged, no per-lane predication.
                        // col is wave-uniform (SALU), provably in [0, WW).
                        const int col = ws_[p] + (ww < nw_[p] ? ww : nw_[p] - 1);
                        const vf2 v =
                            *reinterpret_cast<const vf2*>(rp + (size_t)col * CPS);
                        acc[p].x = fmaxf(acc[p].x, v.x);
                        acc[p].y = fmaxf(acc[p].y, v.y);
                    }
                }
            }
        }
    } else {
        // Generic fallback (never taken for this input distribution).
        for (int hh = 0; hh < nh; ++hh) {
            const float* rp = base + (size_t)hh * (WW * CPS);
#pragma unroll
            for (int p = 0; p < OUTP; ++p) {
                for (int ww = 0; ww < nw_[p]; ++ww) {
                    const vf2 v = *reinterpret_cast<const vf2*>(
                        rp + (size_t)(ws_[p] + ww) * CPS);
                    acc[p].x = fmaxf(acc[p].x, v.x);
                    acc[p].y = fmaxf(acc[p].y, v.y);
                }
            }
        }
    }

    // Stage to LDS in output order: [128 channels][49 bins] (stride 49, odd).
    __shared__ float st[CPS * OUTP * OUTP];
#pragma unroll
    for (int p = 0; p < OUTP; ++p) {
        st[(2 * c2) * 49 + ph * OUTP + p] = acc[p].x;
        st[(2 * c2 + 1) * 49 + ph * OUTP + p] = acc[p].y;
    }
    __syncthreads();

    // Coalesced nontemporal copy-out: 6272 floats = 3136 vf2 = 448 x 7.
    float* ob = out + (size_t)(r * CC + s * CPS) * (OUTP * OUTP);
    const vf2* st2 = reinterpret_cast<const vf2*>(st);
    vf2* ob2 = reinterpret_cast<vf2*>(ob);
#pragma unroll
    for (int k = 0; k < OUTP; ++k) {
        __builtin_nontemporal_store(st2[tid + k * 448], ob2 + tid + k * 448);
    }
}

// Generic no-transpose fallback (only if ws_size is too small for featT).
__global__ __launch_bounds__(256) void roipool_generic(const float* __restrict__ feat,
                                                       const float* __restrict__ rois,
                                                       const int* __restrict__ ridx,
                                                       float* __restrict__ out) {
    const int r = blockIdx.x;
    const int ph = blockIdx.y;
    const int c = threadIdx.x;

    const float4 rv = reinterpret_cast<const float4*>(rois)[r];
    const int x1 = (int)(rv.x * 0.0625f);
    const int y1 = (int)(rv.y * 0.0625f);
    const int x2 = (int)(rv.z * 0.0625f);
    const int y2 = (int)(rv.w * 0.0625f);
    const int b = ridx[r];
    const int Lh = x2 - x1;
    const int Lw = y2 - y1;

    int hs = x1 + (ph * Lh) / OUTP;
    int he = x1 + ((ph + 1) * Lh + OUTP - 1) / OUTP;
    hs = hs < 0 ? 0 : hs;
    he = he > HH ? HH : he;

    float acc[OUTP];
#pragma unroll
    for (int p = 0; p < OUTP; ++p) acc[p] = NEGV;

    for (int h = hs; h < he; ++h) {
#pragma unroll
        for (int p = 0; p < OUTP; ++p) {
            int w0 = y1 + (p * Lw) / OUTP;
            int w1 = y1 + ((p + 1) * Lw + OUTP - 1) / OUTP;
            w0 = w0 < 0 ? 0 : w0;
            w1 = w1 > WW ? WW : w1;
            float m = acc[p];
            for (int w = w0; w < w1; ++w) {
                m = fmaxf(m, feat[((size_t)(b * CC + c) * HH + h) * WW + w]);
            }
            acc[p] = m;
        }
    }

    float* op = out + ((size_t)r * CC + c) * (OUTP * OUTP) + (size_t)ph * OUTP;
#pragma unroll
    for (int p = 0; p < OUTP; ++p) op[p] = acc[p];
}

extern "C" void kernel_launch(void* const* d_in, const int* in_sizes, int n_in,
                              void* d_out, int out_size, void* d_ws, size_t ws_size,
                              hipStream_t stream) {
    const float* features = (const float*)d_in[0];
    const float* rois = (const float*)d_in[1];
    const int* ridx = (const int*)d_in[2];
    float* out = (float*)d_out;
    const int R = in_sizes[1] / 4;

    const size_t tbytes = (size_t)BB * HWSZ * CC * sizeof(float);
    if (ws_size >= tbytes) {
        float* featT = (float*)d_ws;
        dim3 tg((HWSZ + 31) / 32, CC / 32, BB);
        transpose_k<<<tg, dim3(32, 8), 0, stream>>>(features, featT);
        roipool4<<<dim3(CSPLIT, R), 448, 0, stream>>>(featT, rois, ridx, out);
    } else {
        roipool_generic<<<dim3(R, OUTP), 256, 0, stream>>>(features, rois, ridx, out);
    }
}

// Round 6
// 22.935 us; speedup vs baseline: 1.0093x; 1.0093x over previous
//
#include <hip/hip_runtime.h>
#include <cstddef>
#include <cstdint>

// RoIPool: features (B=2, C=256, H=50, W=50) f32, rois (R,4) f32, roi_indices (R,) int
// out (R, C, 7, 7) f32.
// Reference quirk preserved: h-bins from x coords (ri[:,0], ri[:,2]), w-bins from y.
//
// Structure: transpose to (CSPLIT=2, B, H, W, 128) channel-last. Pool kernel:
// one 896-thread block (14 waves) per (slice, roi); wave = (ph, bin-subset)
// so occupancy matches round 3 (28 waves/CU) while lanes do float2 loads.
// Out-of-window loads duplicate in-window elements (max-exact, nh/nw >= 1).
// Wave-uniform scalar branch on nw<=2 skips half the loads for narrow bins.

namespace {
constexpr int OUTP = 7;
constexpr int BB = 2;
constexpr int CC = 256;
constexpr int HH = 50;
constexpr int WW = 50;
constexpr int HWSZ = HH * WW;
constexpr int CSPLIT = 2;
constexpr int CPS = CC / CSPLIT;  // 128 channels per slice
constexpr float NEGV = -3e38f;
typedef float vf2 __attribute__((ext_vector_type(2)));
}  // namespace

// (B, C, H*W) -> (CSPLIT, B, H*W, CPS) tiled transpose via LDS.
__global__ __launch_bounds__(256) void transpose_k(const float* __restrict__ in,
                                                   float* __restrict__ out) {
    __shared__ float tile[32][33];
    const int b = blockIdx.z;
    const int hw0 = blockIdx.x * 32;
    const int c0 = blockIdx.y * 32;
    const int tx = threadIdx.x;
#pragma unroll
    for (int i = threadIdx.y; i < 32; i += 8) {
        const int hw = hw0 + tx;
        float v = 0.0f;
        if (hw < HWSZ) v = in[(size_t)(b * CC + c0 + i) * HWSZ + hw];
        tile[i][tx] = v;
    }
    __syncthreads();
    const int ch = c0 + tx;          // channel this thread writes
    const int s = ch >> 7;           // slice (0..1)
    const int cin = ch & (CPS - 1);  // channel within slice (contiguous in tx)
#pragma unroll
    for (int i = threadIdx.y; i < 32; i += 8) {
        const int hw = hw0 + i;
        if (hw < HWSZ)
            out[((size_t)((s * BB + b) * HWSZ) + hw) * CPS + cin] = tile[tx][i];
    }
}

// Pool: grid (CSPLIT, R), block 896 = 14 waves.
// wave w: ph = w%7; bset = w/7 (0 -> bins 0..3, 1 -> bins 4..6). lane = ch pair.
__global__ __launch_bounds__(896) void roipool6(const float* __restrict__ feat,
                                                const float* __restrict__ rois,
                                                const int* __restrict__ ridx,
                                                float* __restrict__ out) {
    const int s = blockIdx.x;
    const int r = blockIdx.y;
    const int tid = threadIdx.x;
    const int c2 = tid & 63;  // channel-pair index (float2)
    const int wv = __builtin_amdgcn_readfirstlane(tid >> 6);
    const int ph = wv % OUTP;
    const int bset = wv / OUTP;
    const int p0 = bset ? 4 : 0;
    const int np = bset ? 3 : 4;

    const float4 rv = reinterpret_cast<const float4*>(rois)[r];
    int x1 = (int)(rv.x * 0.0625f);
    int y1 = (int)(rv.y * 0.0625f);
    int x2 = (int)(rv.z * 0.0625f);
    int y2 = (int)(rv.w * 0.0625f);
    int b = ridx[r];
    x1 = __builtin_amdgcn_readfirstlane(x1);
    y1 = __builtin_amdgcn_readfirstlane(y1);
    x2 = __builtin_amdgcn_readfirstlane(x2);
    y2 = __builtin_amdgcn_readfirstlane(y2);
    b = __builtin_amdgcn_readfirstlane(b);

    const int Lh = x2 - x1;
    const int Lw = y2 - y1;

    int hs = x1 + (ph * Lh) / OUTP;
    int he = x1 + ((ph + 1) * Lh + OUTP - 1) / OUTP;
    hs = hs < 0 ? 0 : hs;
    he = he > HH ? HH : he;
    const int nh = he - hs;  // >= 1 for this geometry

    __shared__ float st[CPS * OUTP * OUTP];  // [128 ch][49 bins], stride 49 (odd)

    const float* base =
        feat + ((size_t)((s * BB + b) * HWSZ) + (size_t)hs * WW) * CPS + 2 * c2;
    const int rowstride = WW * CPS;

#pragma unroll
    for (int pi = 0; pi < 4; ++pi) {
        if (pi < np) {  // wave-uniform scalar branch
            const int p = p0 + pi;
            int a = y1 + (p * Lw) / OUTP;
            int e = y1 + ((p + 1) * Lw + OUTP - 1) / OUTP;
            a = a < 0 ? 0 : a;
            e = e > WW ? WW : e;
            const int nw = e - a;  // >= 1

            vf2 m = (vf2){NEGV, NEGV};
            const float* bp = base + (size_t)a * CPS;

            if (nw <= 2 && nh <= 4) {
                const int c1 = (nw > 1 ? 1 : 0) * CPS;
#pragma unroll
                for (int hh = 0; hh < 4; ++hh) {
                    if (hh < nh) {  // scalar branch: skipped rows fetch nothing
                        const float* rp = bp + hh * rowstride;
                        const vf2 v0 = *reinterpret_cast<const vf2*>(rp);
                        const vf2 v1 = *reinterpret_cast<const vf2*>(rp + c1);
                        m = __builtin_elementwise_max(m, v0);
                        m = __builtin_elementwise_max(m, v1);
                    }
                }
            } else if (nw <= 4 && nh <= 4) {
                const int c3 = (nw - 1) * CPS;  // duplicate-clamp last col
#pragma unroll
                for (int hh = 0; hh < 4; ++hh) {
                    if (hh < nh) {
                        const float* rp = bp + hh * rowstride;
                        const vf2 v0 = *reinterpret_cast<const vf2*>(rp);
                        const vf2 v1 = *reinterpret_cast<const vf2*>(rp + CPS);
                        const vf2 v2 = *reinterpret_cast<const vf2*>(rp + 2 * CPS);
                        const vf2 v3 = *reinterpret_cast<const vf2*>(rp + c3);
                        m = __builtin_elementwise_max(m, v0);
                        m = __builtin_elementwise_max(m, v1);
                        m = __builtin_elementwise_max(m, v2);
                        m = __builtin_elementwise_max(m, v3);
                    }
                }
            } else {
                // Generic fallback (never taken for this input distribution).
                for (int hh = 0; hh < nh; ++hh) {
                    const float* rp = bp + hh * rowstride;
                    for (int ww = 0; ww < nw; ++ww) {
                        const vf2 v =
                            *reinterpret_cast<const vf2*>(rp + (size_t)ww * CPS);
                        m = __builtin_elementwise_max(m, v);
                    }
                }
            }

            st[(2 * c2) * 49 + ph * OUTP + p] = m.x;
            st[(2 * c2 + 1) * 49 + ph * OUTP + p] = m.y;
        }
    }
    __syncthreads();

    // Coalesced nontemporal copy-out: 3136 vf2 = 448 threads x 7 (waves 0-6).
    if (tid < 448) {
        float* ob = out + (size_t)(r * CC + s * CPS) * (OUTP * OUTP);
        const vf2* st2 = reinterpret_cast<const vf2*>(st);
        vf2* ob2 = reinterpret_cast<vf2*>(ob);
#pragma unroll
        for (int k = 0; k < OUTP; ++k) {
            __builtin_nontemporal_store(st2[tid + k * 448], ob2 + tid + k * 448);
        }
    }
}

// Generic no-transpose fallback (only if ws_size is too small for featT).
__global__ __launch_bounds__(256) void roipool_generic(const float* __restrict__ feat,
                                                       const float* __restrict__ rois,
                                                       const int* __restrict__ ridx,
                                                       float* __restrict__ out) {
    const int r = blockIdx.x;
    const int ph = blockIdx.y;
    const int c = threadIdx.x;

    const float4 rv = reinterpret_cast<const float4*>(rois)[r];
    const int x1 = (int)(rv.x * 0.0625f);
    const int y1 = (int)(rv.y * 0.0625f);
    const int x2 = (int)(rv.z * 0.0625f);
    const int y2 = (int)(rv.w * 0.0625f);
    const int b = ridx[r];
    const int Lh = x2 - x1;
    const int Lw = y2 - y1;

    int hs = x1 + (ph * Lh) / OUTP;
    int he = x1 + ((ph + 1) * Lh + OUTP - 1) / OUTP;
    hs = hs < 0 ? 0 : hs;
    he = he > HH ? HH : he;

    float acc[OUTP];
#pragma unroll
    for (int p = 0; p < OUTP; ++p) acc[p] = NEGV;

    for (int h = hs; h < he; ++h) {
#pragma unroll
        for (int p = 0; p < OUTP; ++p) {
            int w0 = y1 + (p * Lw) / OUTP;
            int w1 = y1 + ((p + 1) * Lw + OUTP - 1) / OUTP;
            w0 = w0 < 0 ? 0 : w0;
            w1 = w1 > WW ? WW : w1;
            float m = acc[p];
            for (int w = w0; w < w1; ++w) {
                m = fmaxf(m, feat[((size_t)(b * CC + c) * HH + h) * WW + w]);
            }
            acc[p] = m;
        }
    }

    float* op = out + ((size_t)r * CC + c) * (OUTP * OUTP) + (size_t)ph * OUTP;
#pragma unroll
    for (int p = 0; p < OUTP; ++p) op[p] = acc[p];
}

extern "C" void kernel_launch(void* const* d_in, const int* in_sizes, int n_in,
                              void* d_out, int out_size, void* d_ws, size_t ws_size,
                              hipStream_t stream) {
    const float* features = (const float*)d_in[0];
    const float* rois = (const float*)d_in[1];
    const int* ridx = (const int*)d_in[2];
    float* out = (float*)d_out;
    const int R = in_sizes[1] / 4;

    const size_t tbytes = (size_t)BB * HWSZ * CC * sizeof(float);
    if (ws_size >= tbytes) {
        float* featT = (float*)d_ws;
        dim3 tg((HWSZ + 31) / 32, CC / 32, BB);
        transpose_k<<<tg, dim3(32, 8), 0, stream>>>(features, featT);
        roipool6<<<dim3(CSPLIT, R), 896, 0, stream>>>(featT, rois, ridx, out);
    } else {
        roipool_generic<<<dim3(R, OUTP), 256, 0, stream>>>(features, rois, ridx, out);
    }
}